// Round 4
// baseline (2507.980 us; speedup 1.0000x reference)
//
#include <hip/hip_runtime.h>

enum { TT = 2048, HH = 64, BB = 64, GG = 256, VV = 256 };

typedef __attribute__((ext_vector_type(8))) short bf16x8;
typedef __attribute__((ext_vector_type(4))) float f32x4;

// LDS-only barrier: does NOT drain vmcnt (global loads/stores stay in flight).
static __device__ __forceinline__ void bar_lds(){
  asm volatile("s_waitcnt lgkmcnt(0)\n\ts_barrier" ::: "memory");
}

static __device__ __forceinline__ unsigned short f2bs(float f){
  unsigned int u = __builtin_bit_cast(unsigned int, f);
  u += 0x7fffu + ((u >> 16) & 1u);
  return (unsigned short)(u >> 16);
}
static __device__ __forceinline__ bf16x8 pack8(const float* v){
  union { unsigned short s[8]; bf16x8 v8; } u;
#pragma unroll
  for (int i = 0; i < 8; i++) u.s[i] = f2bs(v[i]);
  return u.v8;
}

// ---------------- K1: embW[v][g] = emb[v]·w_ih[g] + b_ih[g] + b_hh[g] ----------------
__global__ __launch_bounds__(256) void k_embw(const float* __restrict__ emb,
                                              const float* __restrict__ w_ih,
                                              const float* __restrict__ b_ih,
                                              const float* __restrict__ b_hh,
                                              float* __restrict__ embW){
  int v = blockIdx.x, g = threadIdx.x;
  __shared__ float e[HH];
  if (g < HH) e[g] = emb[v*HH + g];
  bar_lds();
  float acc = b_ih[g] + b_hh[g];
  const float* wr = w_ih + g*HH;
#pragma unroll
  for (int k = 0; k < HH; k += 4){
    float4 w4 = *(const float4*)(wr + k);
    acc = fmaf(e[k],   w4.x, acc); acc = fmaf(e[k+1], w4.y, acc);
    acc = fmaf(e[k+2], w4.z, acc); acc = fmaf(e[k+3], w4.w, acc);
  }
  embW[v*GG + g] = acc;
}

// ---------------- K2: LSTM via MFMA, one WG per 16 batch rows ----------------
// gates(256x16) = W_hh(256x64) @ H^T(64x16) as 16x16x32 bf16 MFMA.
// Wave q owns e in [16q,16q+16): computes i,f,g,o tiles for those e ->
// activations + c/h update fully in-lane; h exchanged via 2.3KB LDS tile.
__global__ __launch_bounds__(256) void k_lstm(const int* __restrict__ x,
                                              const float* __restrict__ embW,
                                              const float* __restrict__ w_hh,
                                              float* __restrict__ hout){
  const int tid  = threadIdx.x;
  const int q    = tid >> 6;       // wave id: e-range [16q, 16q+16)
  const int lane = tid & 63;
  const int n    = lane & 15;      // batch col within group (MFMA col)
  const int quad = lane >> 4;
  const int j    = blockIdx.x*16 + n;   // global batch row

  __shared__ __attribute__((aligned(16))) unsigned short h_lds[16][72]; // [n][e] bf16, 144B stride

  for (int idx = tid; idx < 16*72; idx += 256) ((unsigned short*)h_lds)[idx] = 0;

  // A-fragments: w_hh rows of this wave's 4 gate tiles (G=0..3 -> i,f,g,o), 2 K-chunks
  // A[m=lane&15][k=quad*8+i]  (m120-verified layout)
  bf16x8 A[4][2];
#pragma unroll
  for (int G = 0; G < 4; G++){
    const int grow = G*64 + q*16 + (lane & 15);
#pragma unroll
    for (int kc = 0; kc < 2; kc++){
      float tmp[8];
      const float* src = w_hh + grow*HH + kc*32 + quad*8;
      *(float4*)&tmp[0] = *(const float4*)src;
      *(float4*)&tmp[4] = *(const float4*)(src + 4);
      A[G][kc] = pack8(tmp);
    }
  }

  const int* xrow = x + j*TT;
  int v_nxt = xrow[1];
  const int erow = q*16 + quad*4;        // C/D rows base = e of this lane's 4 states
  f32x4 gx[4];
  {
    int v0 = xrow[0];
#pragma unroll
    for (int G = 0; G < 4; G++)
      gx[G] = *(const f32x4*)(embW + v0*GG + G*64 + erow);
  }
  float cs[4] = {0.f, 0.f, 0.f, 0.f};
  float* hb = hout + (size_t)j*TT*HH + erow;

  bar_lds();

  for (int t = 0; t < TT; t++){
    // prefetch gx(t+1) and x index (t+2); fire-and-forget until next iter
    f32x4 gxn[4];
#pragma unroll
    for (int G = 0; G < 4; G++)
      gxn[G] = *(const f32x4*)(embW + v_nxt*GG + G*64 + erow);
    int v_nn = xrow[(t + 2 < TT) ? (t + 2) : (TT - 1)];

    // B-fragments: B[k=quad*8+i][n=lane&15] from h_lds[n][k] (bank-balanced, 16B aligned)
    bf16x8 B0 = *(const bf16x8*)&h_lds[n][quad*8];
    bf16x8 B1 = *(const bf16x8*)&h_lds[n][32 + quad*8];

    f32x4 acc[4];
#pragma unroll
    for (int G = 0; G < 4; G++){
      acc[G] = __builtin_amdgcn_mfma_f32_16x16x32_bf16(A[G][0], B0, gx[G],   0, 0, 0);
      acc[G] = __builtin_amdgcn_mfma_f32_16x16x32_bf16(A[G][1], B1, acc[G],  0, 0, 0);
    }

    float hn[4];
#pragma unroll
    for (int r = 0; r < 4; r++){
      float i_ = 1.f/(1.f + __expf(-acc[0][r]));
      float f_ = 1.f/(1.f + __expf(-acc[1][r]));
      float g_ = 1.f - 2.f/(__expf(2.f*acc[2][r]) + 1.f);
      float o_ = 1.f/(1.f + __expf(-acc[3][r]));
      cs[r] = fmaf(f_, cs[r], i_*g_);
      hn[r] = o_*(1.f - 2.f/(__expf(2.f*cs[r]) + 1.f));
    }

    *(float4*)(hb + (size_t)t*HH) = make_float4(hn[0], hn[1], hn[2], hn[3]); // no vmcnt drain
    bar_lds();                      // all waves' B-reads done before h overwrite
    unsigned int p0 = (unsigned int)f2bs(hn[0]) | ((unsigned int)f2bs(hn[1]) << 16);
    unsigned int p1 = (unsigned int)f2bs(hn[2]) | ((unsigned int)f2bs(hn[3]) << 16);
    *(uint2*)&h_lds[n][erow] = make_uint2(p0, p1);
    bar_lds();                      // h visible to all waves

#pragma unroll
    for (int G = 0; G < 4; G++) gx[G] = gxn[G];
    v_nxt = v_nn;
  }
}

// ---------------- K3: fused MHA level, one workgroup per time step t ----------------
__global__ __launch_bounds__(256) void k_mha(const float* __restrict__ hin,
                                             const float* __restrict__ wqkv,
                                             const float* __restrict__ bqkv,
                                             const float* __restrict__ wo,
                                             const float* __restrict__ bo,
                                             float* __restrict__ hout){
  int t = blockIdx.x, tid = threadIdx.x;
  __shared__ float xta[BB][HH];    // x column, later reused for attention output (16KB)
  __shared__ float qkvs[BB][192];  // qkv rows (48KB)

  float wq[HH]; float bq = 0.f;
  if (tid < 192){
#pragma unroll
    for (int k = 0; k < HH; k += 4)
      *(float4*)&wq[k] = *(const float4*)(wqkv + tid*HH + k);
    bq = bqkv[tid];
  }
  {
    int r = tid >> 2, q = tid & 3;
    const float* p = hin + (size_t)(r*TT + t)*HH + q*16;
#pragma unroll
    for (int jj = 0; jj < 16; jj += 4)
      *(float4*)&xta[r][q*16 + jj] = *(const float4*)(p + jj);
  }
  bar_lds();
  if (tid < 192){
#pragma unroll 4
    for (int b = 0; b < BB; b++){
      float acc = bq;
#pragma unroll
      for (int k = 0; k < HH; k += 4){
        float4 xv = *(const float4*)&xta[b][k];
        acc = fmaf(wq[k],   xv.x, acc); acc = fmaf(wq[k+1], xv.y, acc);
        acc = fmaf(wq[k+2], xv.z, acc); acc = fmaf(wq[k+3], xv.w, acc);
      }
      qkvs[b][tid] = acc;
    }
  }
  bar_lds();
  {
    int hd = tid >> 6, l = tid & 63;
    int qo = hd*16, ko = 64 + hd*16, vo = 128 + hd*16;
    float4 q0 = *(const float4*)&qkvs[l][qo];
    float4 q1 = *(const float4*)&qkvs[l][qo+4];
    float4 q2 = *(const float4*)&qkvs[l][qo+8];
    float4 q3 = *(const float4*)&qkvs[l][qo+12];
    float S[BB];
#pragma unroll
    for (int m = 0; m < BB; m++){
      float4 k0 = *(const float4*)&qkvs[m][ko];
      float4 k1 = *(const float4*)&qkvs[m][ko+4];
      float4 k2 = *(const float4*)&qkvs[m][ko+8];
      float4 k3 = *(const float4*)&qkvs[m][ko+12];
      float d;
      d = q0.x*k0.x;         d = fmaf(q0.y,k0.y,d); d = fmaf(q0.z,k0.z,d); d = fmaf(q0.w,k0.w,d);
      d = fmaf(q1.x,k1.x,d); d = fmaf(q1.y,k1.y,d); d = fmaf(q1.z,k1.z,d); d = fmaf(q1.w,k1.w,d);
      d = fmaf(q2.x,k2.x,d); d = fmaf(q2.y,k2.y,d); d = fmaf(q2.z,k2.z,d); d = fmaf(q2.w,k2.w,d);
      d = fmaf(q3.x,k3.x,d); d = fmaf(q3.y,k3.y,d); d = fmaf(q3.z,k3.z,d); d = fmaf(q3.w,k3.w,d);
      S[m] = 0.25f*d;
    }
    float mx = S[0];
#pragma unroll
    for (int m = 1; m < BB; m++) mx = fmaxf(mx, S[m]);
    float sum = 0.f;
#pragma unroll
    for (int m = 0; m < BB; m++){ S[m] = __expf(S[m] - mx); sum += S[m]; }
    float inv = 1.f/sum;
    float4 a0 = make_float4(0,0,0,0), a1 = a0, a2 = a0, a3 = a0;
#pragma unroll
    for (int m = 0; m < BB; m++){
      float s = S[m];
      float4 v0 = *(const float4*)&qkvs[m][vo];
      float4 v1 = *(const float4*)&qkvs[m][vo+4];
      float4 v2 = *(const float4*)&qkvs[m][vo+8];
      float4 v3 = *(const float4*)&qkvs[m][vo+12];
      a0.x = fmaf(s,v0.x,a0.x); a0.y = fmaf(s,v0.y,a0.y); a0.z = fmaf(s,v0.z,a0.z); a0.w = fmaf(s,v0.w,a0.w);
      a1.x = fmaf(s,v1.x,a1.x); a1.y = fmaf(s,v1.y,a1.y); a1.z = fmaf(s,v1.z,a1.z); a1.w = fmaf(s,v1.w,a1.w);
      a2.x = fmaf(s,v2.x,a2.x); a2.y = fmaf(s,v2.y,a2.y); a2.z = fmaf(s,v2.z,a2.z); a2.w = fmaf(s,v2.w,a2.w);
      a3.x = fmaf(s,v3.x,a3.x); a3.y = fmaf(s,v3.y,a3.y); a3.z = fmaf(s,v3.z,a3.z); a3.w = fmaf(s,v3.w,a3.w);
    }
    a0.x*=inv; a0.y*=inv; a0.z*=inv; a0.w*=inv;
    a1.x*=inv; a1.y*=inv; a1.z*=inv; a1.w*=inv;
    a2.x*=inv; a2.y*=inv; a2.z*=inv; a2.w*=inv;
    a3.x*=inv; a3.y*=inv; a3.z*=inv; a3.w*=inv;
    bar_lds();
    *(float4*)&xta[l][qo]    = a0;
    *(float4*)&xta[l][qo+4]  = a1;
    *(float4*)&xta[l][qo+8]  = a2;
    *(float4*)&xta[l][qo+12] = a3;
  }
  bar_lds();
  {
    int c = tid & 63, wg = tid >> 6;
    float wor[HH];
#pragma unroll
    for (int k = 0; k < HH; k += 4)
      *(float4*)&wor[k] = *(const float4*)(wo + c*HH + k);
    float bo4 = bo[c];
#pragma unroll 2
    for (int jj = 0; jj < 16; jj++){
      int b = wg*16 + jj;
      float acc = bo4;
#pragma unroll
      for (int k = 0; k < HH; k += 4){
        float4 xv = *(const float4*)&xta[b][k];
        acc = fmaf(wor[k],   xv.x, acc); acc = fmaf(wor[k+1], xv.y, acc);
        acc = fmaf(wor[k+2], xv.z, acc); acc = fmaf(wor[k+3], xv.w, acc);
      }
      hout[(size_t)(b*TT + t)*HH + c] = acc;
    }
  }
}

// ---------------- K4: LayerNorm + FC (ln folded into fc_w registers) ----------------
__global__ __launch_bounds__(256) void k_fc(const float* __restrict__ hin,
                                            const float* __restrict__ ln_g,
                                            const float* __restrict__ ln_b,
                                            const float* __restrict__ fc_w,
                                            const float* __restrict__ fc_b,
                                            float* __restrict__ out){
  int tid = threadIdx.x;
  __shared__ float tile[64][68];
  __shared__ float ps[64][4];
  __shared__ float pq[64][4];
  __shared__ float mu[64], rs[64];
  float w[HH];
  float wsum = 0.f, bias2 = fc_b[tid];
#pragma unroll
  for (int k = 0; k < HH; k += 4){
    float4 wv = *(const float4*)(fc_w + tid*HH + k);
    float4 gv = *(const float4*)(ln_g + k);
    float4 bv = *(const float4*)(ln_b + k);
    bias2 = fmaf(bv.x, wv.x, bias2); bias2 = fmaf(bv.y, wv.y, bias2);
    bias2 = fmaf(bv.z, wv.z, bias2); bias2 = fmaf(bv.w, wv.w, bias2);
    w[k]   = gv.x*wv.x; w[k+1] = gv.y*wv.y;
    w[k+2] = gv.z*wv.z; w[k+3] = gv.w*wv.w;
    wsum += w[k] + w[k+1] + w[k+2] + w[k+3];
  }
  int r = tid >> 2, q = tid & 3;
  for (int ti = 0; ti < 4; ti++){
    int rowbase = blockIdx.x*256 + ti*64;
    const float* p = hin + (size_t)(rowbase + r)*HH + q*16;
    float xv[16];
#pragma unroll
    for (int jj = 0; jj < 16; jj += 4)
      *(float4*)&xv[jj] = *(const float4*)(p + jj);
    float s1 = 0.f, s2 = 0.f;
#pragma unroll
    for (int jj = 0; jj < 16; jj++){ s1 += xv[jj]; s2 = fmaf(xv[jj], xv[jj], s2); }
#pragma unroll
    for (int jj = 0; jj < 16; jj += 4)
      *(float4*)&tile[r][q*16 + jj] = *(const float4*)&xv[jj];
    ps[r][q] = s1; pq[r][q] = s2;
    bar_lds();
    if (tid < 64){
      float4 a  = *(const float4*)&ps[tid][0];
      float4 b4 = *(const float4*)&pq[tid][0];
      float m = (a.x + a.y + a.z + a.w) * (1.f/64.f);
      float v = (b4.x + b4.y + b4.z + b4.w) * (1.f/64.f) - m*m;
      mu[tid] = m;
      rs[tid] = rsqrtf(v + 1e-5f);
    }
    bar_lds();
#pragma unroll 2
    for (int rr = 0; rr < 64; rr++){
      float acc = 0.f;
#pragma unroll
      for (int k = 0; k < HH; k += 4){
        float4 x4 = *(const float4*)&tile[rr][k];
        acc = fmaf(w[k],   x4.x, acc); acc = fmaf(w[k+1], x4.y, acc);
        acc = fmaf(w[k+2], x4.z, acc); acc = fmaf(w[k+3], x4.w, acc);
      }
      float o = rs[rr]*(acc - mu[rr]*wsum) + bias2;
      out[(size_t)(rowbase + rr)*VV + tid] = o;
    }
    bar_lds();
  }
}

extern "C" void kernel_launch(void* const* d_in, const int* in_sizes, int n_in,
                              void* d_out, int out_size, void* d_ws, size_t ws_size,
                              hipStream_t stream){
  (void)in_sizes; (void)n_in; (void)out_size; (void)ws_size;
  const int*   x    = (const int*)d_in[0];
  const float* emb  = (const float*)d_in[1];
  const float* w_ih = (const float*)d_in[2];
  const float* w_hh = (const float*)d_in[3];
  const float* b_ih = (const float*)d_in[4];
  const float* b_hh = (const float*)d_in[5];
  const float* wqkv = (const float*)d_in[6];
  const float* bqkv = (const float*)d_in[7];
  const float* wo   = (const float*)d_in[8];
  const float* bo   = (const float*)d_in[9];
  const float* ln_g = (const float*)d_in[10];
  const float* ln_b = (const float*)d_in[11];
  const float* fc_w = (const float*)d_in[12];
  const float* fc_b = (const float*)d_in[13];

  char* ws = (char*)d_ws;
  float* embW = (float*)ws;                               // 256*256*4 = 256KB
  float* bufA = (float*)(ws + (1<<20));                   // 32MB fp32 (B,T,H)
  float* bufB = bufA + (size_t)BB*TT*HH;                  // 32MB fp32

  k_embw<<<VV,    256, 0, stream>>>(emb, w_ih, b_ih, b_hh, embW);
  k_lstm<<<BB/16, 256, 0, stream>>>(x, embW, w_hh, bufA);
  k_mha <<<TT,    256, 0, stream>>>(bufA, wqkv,          bqkv,       wo,         bo,      bufB);
  k_mha <<<TT,    256, 0, stream>>>(bufB, wqkv + 192*64, bqkv + 192, wo + 64*64, bo + 64, bufA);
  k_fc  <<<512,   256, 0, stream>>>(bufA, ln_g, ln_b, fc_w, fc_b, (float*)d_out);
}

// Round 5
// 1865.869 us; speedup vs baseline: 1.3441x; 1.3441x over previous
//
#include <hip/hip_runtime.h>

enum { TT = 2048, HH = 64, BB = 64, GG = 256, VV = 256 };

typedef __attribute__((ext_vector_type(8))) short bf16x8;
typedef __attribute__((ext_vector_type(4))) float f32x4;

// LDS-only barrier: does NOT drain vmcnt (global loads/stores stay in flight).
static __device__ __forceinline__ void bar_lds(){
  asm volatile("s_waitcnt lgkmcnt(0)\n\ts_barrier" ::: "memory");
}
static __device__ __forceinline__ float frcp(float x){ return __builtin_amdgcn_rcpf(x); }

static __device__ __forceinline__ unsigned short f2bs(float f){
  unsigned int u = __builtin_bit_cast(unsigned int, f);
  u += 0x7fffu + ((u >> 16) & 1u);
  return (unsigned short)(u >> 16);
}
static __device__ __forceinline__ bf16x8 pack8(const float* v){
  union { unsigned short s[8]; bf16x8 v8; } u;
#pragma unroll
  for (int i = 0; i < 8; i++) u.s[i] = f2bs(v[i]);
  return u.v8;
}

// ---------------- K1: embW[v][g] = emb[v]·w_ih[g] + b_ih[g] + b_hh[g] ----------------
__global__ __launch_bounds__(256) void k_embw(const float* __restrict__ emb,
                                              const float* __restrict__ w_ih,
                                              const float* __restrict__ b_ih,
                                              const float* __restrict__ b_hh,
                                              float* __restrict__ embW){
  int v = blockIdx.x, g = threadIdx.x;
  __shared__ float e[HH];
  if (g < HH) e[g] = emb[v*HH + g];
  bar_lds();
  float acc = b_ih[g] + b_hh[g];
  const float* wr = w_ih + g*HH;
#pragma unroll
  for (int k = 0; k < HH; k += 4){
    float4 w4 = *(const float4*)(wr + k);
    acc = fmaf(e[k],   w4.x, acc); acc = fmaf(e[k+1], w4.y, acc);
    acc = fmaf(e[k+2], w4.z, acc); acc = fmaf(e[k+3], w4.w, acc);
  }
  embW[v*GG + g] = acc;
}

// ---------------- K2: LSTM via MFMA, one WG per 16 batch rows ----------------
// gates(256x16) = W_hh(256x64) @ H^T(64x16) as 16x16x32 bf16 MFMA.
// Wave q owns e in [16q,16q+16); i,f,g,o tiles land in-lane. h exchanged via
// double-buffered 2.3KB LDS tile -> ONE barrier per step. All reciprocals via
// v_rcp_f32 (IEEE div expansion was the round-4 VALU wall).
__global__ __launch_bounds__(256) void k_lstm(const int* __restrict__ x,
                                              const float* __restrict__ embW,
                                              const float* __restrict__ w_hh,
                                              float* __restrict__ hout){
  const int tid  = threadIdx.x;
  const int q    = tid >> 6;       // wave id: e-range [16q, 16q+16)
  const int lane = tid & 63;
  const int n    = lane & 15;      // batch col within group (MFMA col)
  const int quad = lane >> 4;
  const int j    = blockIdx.x*16 + n;   // global batch row

  __shared__ __attribute__((aligned(16))) unsigned short h_lds[2][16][72]; // [buf][n][e] bf16

  for (int idx = tid; idx < 2*16*72; idx += 256) ((unsigned short*)h_lds)[idx] = 0;

  // A-fragments: w_hh rows of this wave's 4 gate tiles (G=0..3 -> i,f,g,o), 2 K-chunks
  bf16x8 A[4][2];
#pragma unroll
  for (int G = 0; G < 4; G++){
    const int grow = G*64 + q*16 + (lane & 15);
#pragma unroll
    for (int kc = 0; kc < 2; kc++){
      float tmp[8];
      const float* src = w_hh + grow*HH + kc*32 + quad*8;
      *(float4*)&tmp[0] = *(const float4*)src;
      *(float4*)&tmp[4] = *(const float4*)(src + 4);
      A[G][kc] = pack8(tmp);
    }
  }

  const int* xrow = x + j*TT;
  int v_nxt = xrow[1];
  const int erow = q*16 + quad*4;        // C/D rows base = e of this lane's 4 states
  f32x4 gx[4];
  {
    int v0 = xrow[0];
#pragma unroll
    for (int G = 0; G < 4; G++)
      gx[G] = *(const f32x4*)(embW + v0*GG + G*64 + erow);
  }
  float cs[4] = {0.f, 0.f, 0.f, 0.f};
  float* hb = hout + (size_t)j*TT*HH + erow;

  bar_lds();

#pragma unroll 2
  for (int t = 0; t < TT; t++){
    const int pb = t & 1;
    // prefetch gx(t+1) and x index (t+2); fire-and-forget until end of iter
    f32x4 gxn[4];
#pragma unroll
    for (int G = 0; G < 4; G++)
      gxn[G] = *(const f32x4*)(embW + v_nxt*GG + G*64 + erow);
    int v_nn = xrow[(t + 2 < TT) ? (t + 2) : (TT - 1)];

    // B-fragments from the buffer written at t-1
    bf16x8 B0 = *(const bf16x8*)&h_lds[pb^1][n][quad*8];
    bf16x8 B1 = *(const bf16x8*)&h_lds[pb^1][n][32 + quad*8];

    f32x4 acc[4];
#pragma unroll
    for (int G = 0; G < 4; G++){
      acc[G] = __builtin_amdgcn_mfma_f32_16x16x32_bf16(A[G][0], B0, gx[G],   0, 0, 0);
      acc[G] = __builtin_amdgcn_mfma_f32_16x16x32_bf16(A[G][1], B1, acc[G],  0, 0, 0);
    }

    float hn[4];
#pragma unroll
    for (int r = 0; r < 4; r++){
      float i_ = frcp(1.f + __expf(-acc[0][r]));
      float f_ = frcp(1.f + __expf(-acc[1][r]));
      float g_ = fmaf(-2.f, frcp(__expf(2.f*acc[2][r]) + 1.f), 1.f);
      float o_ = frcp(1.f + __expf(-acc[3][r]));
      cs[r] = fmaf(f_, cs[r], i_*g_);
      float th = fmaf(-2.f, frcp(__expf(2.f*cs[r]) + 1.f), 1.f);
      hn[r] = o_*th;
    }

    *(float4*)(hb + (size_t)t*HH) = make_float4(hn[0], hn[1], hn[2], hn[3]); // no vmcnt drain
    // write h(t) into buffer pb; readers of pb^1 (this step) unaffected
    unsigned int p0 = (unsigned int)f2bs(hn[0]) | ((unsigned int)f2bs(hn[1]) << 16);
    unsigned int p1 = (unsigned int)f2bs(hn[2]) | ((unsigned int)f2bs(hn[3]) << 16);
    *(uint2*)&h_lds[pb][n][erow] = make_uint2(p0, p1);
    bar_lds();                      // single barrier: h(t) visible, and orders write(t+1) after reads(t)

#pragma unroll
    for (int G = 0; G < 4; G++) gx[G] = gxn[G];
    v_nxt = v_nn;
  }
}

// ---------------- K3: fused MHA level, one workgroup per time step t ----------------
__global__ __launch_bounds__(256) void k_mha(const float* __restrict__ hin,
                                             const float* __restrict__ wqkv,
                                             const float* __restrict__ bqkv,
                                             const float* __restrict__ wo,
                                             const float* __restrict__ bo,
                                             float* __restrict__ hout){
  int t = blockIdx.x, tid = threadIdx.x;
  __shared__ float xta[BB][HH];    // x column, later reused for attention output (16KB)
  __shared__ float qkvs[BB][192];  // qkv rows (48KB)

  float wq[HH]; float bq = 0.f;
  if (tid < 192){
#pragma unroll
    for (int k = 0; k < HH; k += 4)
      *(float4*)&wq[k] = *(const float4*)(wqkv + tid*HH + k);
    bq = bqkv[tid];
  }
  {
    int r = tid >> 2, q = tid & 3;
    const float* p = hin + (size_t)(r*TT + t)*HH + q*16;
#pragma unroll
    for (int jj = 0; jj < 16; jj += 4)
      *(float4*)&xta[r][q*16 + jj] = *(const float4*)(p + jj);
  }
  bar_lds();
  if (tid < 192){
#pragma unroll 4
    for (int b = 0; b < BB; b++){
      float acc = bq;
#pragma unroll
      for (int k = 0; k < HH; k += 4){
        float4 xv = *(const float4*)&xta[b][k];
        acc = fmaf(wq[k],   xv.x, acc); acc = fmaf(wq[k+1], xv.y, acc);
        acc = fmaf(wq[k+2], xv.z, acc); acc = fmaf(wq[k+3], xv.w, acc);
      }
      qkvs[b][tid] = acc;
    }
  }
  bar_lds();
  {
    int hd = tid >> 6, l = tid & 63;
    int qo = hd*16, ko = 64 + hd*16, vo = 128 + hd*16;
    float4 q0 = *(const float4*)&qkvs[l][qo];
    float4 q1 = *(const float4*)&qkvs[l][qo+4];
    float4 q2 = *(const float4*)&qkvs[l][qo+8];
    float4 q3 = *(const float4*)&qkvs[l][qo+12];
    float S[BB];
#pragma unroll
    for (int m = 0; m < BB; m++){
      float4 k0 = *(const float4*)&qkvs[m][ko];
      float4 k1 = *(const float4*)&qkvs[m][ko+4];
      float4 k2 = *(const float4*)&qkvs[m][ko+8];
      float4 k3 = *(const float4*)&qkvs[m][ko+12];
      float d;
      d = q0.x*k0.x;         d = fmaf(q0.y,k0.y,d); d = fmaf(q0.z,k0.z,d); d = fmaf(q0.w,k0.w,d);
      d = fmaf(q1.x,k1.x,d); d = fmaf(q1.y,k1.y,d); d = fmaf(q1.z,k1.z,d); d = fmaf(q1.w,k1.w,d);
      d = fmaf(q2.x,k2.x,d); d = fmaf(q2.y,k2.y,d); d = fmaf(q2.z,k2.z,d); d = fmaf(q2.w,k2.w,d);
      d = fmaf(q3.x,k3.x,d); d = fmaf(q3.y,k3.y,d); d = fmaf(q3.z,k3.z,d); d = fmaf(q3.w,k3.w,d);
      S[m] = 0.25f*d;
    }
    float mx = S[0];
#pragma unroll
    for (int m = 1; m < BB; m++) mx = fmaxf(mx, S[m]);
    float sum = 0.f;
#pragma unroll
    for (int m = 0; m < BB; m++){ S[m] = __expf(S[m] - mx); sum += S[m]; }
    float inv = frcp(sum);
    float4 a0 = make_float4(0,0,0,0), a1 = a0, a2 = a0, a3 = a0;
#pragma unroll
    for (int m = 0; m < BB; m++){
      float s = S[m];
      float4 v0 = *(const float4*)&qkvs[m][vo];
      float4 v1 = *(const float4*)&qkvs[m][vo+4];
      float4 v2 = *(const float4*)&qkvs[m][vo+8];
      float4 v3 = *(const float4*)&qkvs[m][vo+12];
      a0.x = fmaf(s,v0.x,a0.x); a0.y = fmaf(s,v0.y,a0.y); a0.z = fmaf(s,v0.z,a0.z); a0.w = fmaf(s,v0.w,a0.w);
      a1.x = fmaf(s,v1.x,a1.x); a1.y = fmaf(s,v1.y,a1.y); a1.z = fmaf(s,v1.z,a1.z); a1.w = fmaf(s,v1.w,a1.w);
      a2.x = fmaf(s,v2.x,a2.x); a2.y = fmaf(s,v2.y,a2.y); a2.z = fmaf(s,v2.z,a2.z); a2.w = fmaf(s,v2.w,a2.w);
      a3.x = fmaf(s,v3.x,a3.x); a3.y = fmaf(s,v3.y,a3.y); a3.z = fmaf(s,v3.z,a3.z); a3.w = fmaf(s,v3.w,a3.w);
    }
    a0.x*=inv; a0.y*=inv; a0.z*=inv; a0.w*=inv;
    a1.x*=inv; a1.y*=inv; a1.z*=inv; a1.w*=inv;
    a2.x*=inv; a2.y*=inv; a2.z*=inv; a2.w*=inv;
    a3.x*=inv; a3.y*=inv; a3.z*=inv; a3.w*=inv;
    bar_lds();
    *(float4*)&xta[l][qo]    = a0;
    *(float4*)&xta[l][qo+4]  = a1;
    *(float4*)&xta[l][qo+8]  = a2;
    *(float4*)&xta[l][qo+12] = a3;
  }
  bar_lds();
  {
    int c = tid & 63, wg = tid >> 6;
    float wor[HH];
#pragma unroll
    for (int k = 0; k < HH; k += 4)
      *(float4*)&wor[k] = *(const float4*)(wo + c*HH + k);
    float bo4 = bo[c];
#pragma unroll 2
    for (int jj = 0; jj < 16; jj++){
      int b = wg*16 + jj;
      float acc = bo4;
#pragma unroll
      for (int k = 0; k < HH; k += 4){
        float4 xv = *(const float4*)&xta[b][k];
        acc = fmaf(wor[k],   xv.x, acc); acc = fmaf(wor[k+1], xv.y, acc);
        acc = fmaf(wor[k+2], xv.z, acc); acc = fmaf(wor[k+3], xv.w, acc);
      }
      hout[(size_t)(b*TT + t)*HH + c] = acc;
    }
  }
}

// ---------------- K4: LayerNorm + FC (ln folded into fc_w registers) ----------------
__global__ __launch_bounds__(256) void k_fc(const float* __restrict__ hin,
                                            const float* __restrict__ ln_g,
                                            const float* __restrict__ ln_b,
                                            const float* __restrict__ fc_w,
                                            const float* __restrict__ fc_b,
                                            float* __restrict__ out){
  int tid = threadIdx.x;
  __shared__ float tile[64][68];
  __shared__ float ps[64][4];
  __shared__ float pq[64][4];
  __shared__ float mu[64], rs[64];
  float w[HH];
  float wsum = 0.f, bias2 = fc_b[tid];
#pragma unroll
  for (int k = 0; k < HH; k += 4){
    float4 wv = *(const float4*)(fc_w + tid*HH + k);
    float4 gv = *(const float4*)(ln_g + k);
    float4 bv = *(const float4*)(ln_b + k);
    bias2 = fmaf(bv.x, wv.x, bias2); bias2 = fmaf(bv.y, wv.y, bias2);
    bias2 = fmaf(bv.z, wv.z, bias2); bias2 = fmaf(bv.w, wv.w, bias2);
    w[k]   = gv.x*wv.x; w[k+1] = gv.y*wv.y;
    w[k+2] = gv.z*wv.z; w[k+3] = gv.w*wv.w;
    wsum += w[k] + w[k+1] + w[k+2] + w[k+3];
  }
  int r = tid >> 2, q = tid & 3;
  for (int ti = 0; ti < 4; ti++){
    int rowbase = blockIdx.x*256 + ti*64;
    const float* p = hin + (size_t)(rowbase + r)*HH + q*16;
    float xv[16];
#pragma unroll
    for (int jj = 0; jj < 16; jj += 4)
      *(float4*)&xv[jj] = *(const float4*)(p + jj);
    float s1 = 0.f, s2 = 0.f;
#pragma unroll
    for (int jj = 0; jj < 16; jj++){ s1 += xv[jj]; s2 = fmaf(xv[jj], xv[jj], s2); }
#pragma unroll
    for (int jj = 0; jj < 16; jj += 4)
      *(float4*)&tile[r][q*16 + jj] = *(const float4*)&xv[jj];
    ps[r][q] = s1; pq[r][q] = s2;
    bar_lds();
    if (tid < 64){
      float4 a  = *(const float4*)&ps[tid][0];
      float4 b4 = *(const float4*)&pq[tid][0];
      float m = (a.x + a.y + a.z + a.w) * (1.f/64.f);
      float v = (b4.x + b4.y + b4.z + b4.w) * (1.f/64.f) - m*m;
      mu[tid] = m;
      rs[tid] = rsqrtf(v + 1e-5f);
    }
    bar_lds();
#pragma unroll 2
    for (int rr = 0; rr < 64; rr++){
      float acc = 0.f;
#pragma unroll
      for (int k = 0; k < HH; k += 4){
        float4 x4 = *(const float4*)&tile[rr][k];
        acc = fmaf(w[k],   x4.x, acc); acc = fmaf(w[k+1], x4.y, acc);
        acc = fmaf(w[k+2], x4.z, acc); acc = fmaf(w[k+3], x4.w, acc);
      }
      float o = rs[rr]*(acc - mu[rr]*wsum) + bias2;
      out[(size_t)(rowbase + rr)*VV + tid] = o;
    }
    bar_lds();
  }
}

extern "C" void kernel_launch(void* const* d_in, const int* in_sizes, int n_in,
                              void* d_out, int out_size, void* d_ws, size_t ws_size,
                              hipStream_t stream){
  (void)in_sizes; (void)n_in; (void)out_size; (void)ws_size;
  const int*   x    = (const int*)d_in[0];
  const float* emb  = (const float*)d_in[1];
  const float* w_ih = (const float*)d_in[2];
  const float* w_hh = (const float*)d_in[3];
  const float* b_ih = (const float*)d_in[4];
  const float* b_hh = (const float*)d_in[5];
  const float* wqkv = (const float*)d_in[6];
  const float* bqkv = (const float*)d_in[7];
  const float* wo   = (const float*)d_in[8];
  const float* bo   = (const float*)d_in[9];
  const float* ln_g = (const float*)d_in[10];
  const float* ln_b = (const float*)d_in[11];
  const float* fc_w = (const float*)d_in[12];
  const float* fc_b = (const float*)d_in[13];

  char* ws = (char*)d_ws;
  float* embW = (float*)ws;                               // 256*256*4 = 256KB
  float* bufA = (float*)(ws + (1<<20));                   // 32MB fp32 (B,T,H)
  float* bufB = bufA + (size_t)BB*TT*HH;                  // 32MB fp32

  k_embw<<<VV,    256, 0, stream>>>(emb, w_ih, b_ih, b_hh, embW);
  k_lstm<<<BB/16, 256, 0, stream>>>(x, embW, w_hh, bufA);
  k_mha <<<TT,    256, 0, stream>>>(bufA, wqkv,          bqkv,       wo,         bo,      bufB);
  k_mha <<<TT,    256, 0, stream>>>(bufB, wqkv + 192*64, bqkv + 192, wo + 64*64, bo + 64, bufA);
  k_fc  <<<512,   256, 0, stream>>>(bufA, ln_g, ln_b, fc_w, fc_b, (float*)d_out);
}